// Round 10
// baseline (150.970 us; speedup 1.0000x reference)
//
#include <hip/hip_runtime.h>
#include <hip/hip_bf16.h>
#include <cstdint>
#include <cstddef>

#define TOKENS 8192
#define IN_F   1024
#define OUT_F  1024
#define ROWB   7168          // row stride bytes: 5120 i8 (P1..P5) + 2048 bf16 (silu)
#define BUF    8192          // LDS buffer: B 128x64B

typedef __attribute__((ext_vector_type(4))) float          f32x4;
typedef __attribute__((ext_vector_type(4))) float          float4v;
typedef __attribute__((ext_vector_type(4))) int            i32x4;
typedef __attribute__((ext_vector_type(8))) __bf16         bf16x8;
typedef __attribute__((ext_vector_type(8))) unsigned short ushort8;
typedef __attribute__((ext_vector_type(8))) char           char8;

__device__ __forceinline__ unsigned short f2bf(float f) {
    unsigned int u = __builtin_bit_cast(unsigned int, f);
    u += 0x7FFFu + ((u >> 16) & 1u);
    return (unsigned short)(u >> 16);
}

// ============================================================================
// Kernel 1: activations -> interleaved rows Arow[b][0..5119]=P1..P5 i8 (x63.5),
//           Arow[b][5120..7167] = silu bf16.  Fast tanh via __expf.
// ============================================================================
__global__ __launch_bounds__(256) void act_kernel(const float* __restrict__ x,
                                                  char* __restrict__ Arow) {
    int gid = blockIdx.x * 256 + threadIdx.x;
    int b   = gid >> 7;
    int i8  = (gid & 127) << 3;

    const float* xp = x + (size_t)b * IN_F + i8;
    float xs[8];
    *(float4v*)&xs[0] = *(const float4v*)xp;
    *(float4v*)&xs[4] = *(const float4v*)(xp + 4);

    unsigned short sres[8];
    char8 q[5];
    #pragma unroll
    for (int e = 0; e < 8; ++e) {
        float v  = xs[e];
        float s  = v / (1.f + __expf(-v));
        float t  = 1.f - 2.f / (1.f + __expf(2.f * v));   // tanh(v), exact at +-inf
        float p1 = 2.f * t;
        float p2 = (12.f / 24.f) * t * p1 - (8.f / 24.f) * 1.f;
        float p3 = (64.f / 120.f) * t * p2 - (48.f / 120.f) * p1;
        float p4 = (180.f / 336.f) * t * p3 - (144.f / 336.f) * p2;
        float p5 = (384.f / 720.f) * t * p4 - (320.f / 720.f) * p3;
        sres[e] = f2bf(s);
        q[0][e] = (char)__float2int_rn(p1 * 63.5f);
        q[1][e] = (char)__float2int_rn(p2 * 63.5f);
        q[2][e] = (char)__float2int_rn(p3 * 63.5f);
        q[3][e] = (char)__float2int_rn(p4 * 63.5f);
        q[4][e] = (char)__float2int_rn(p5 * 63.5f);
    }
    char* row = Arow + (size_t)b * ROWB;
    #pragma unroll
    for (int k = 0; k < 5; ++k)
        *(char8*)(row + k * 1024 + i8) = q[k];
    *(ushort8*)(row + 5120 + i8 * 2) = *(const ushort8*)&sres[0];
}

// ============================================================================
// Kernel 2: weights -> Brow[o][0..5119]=C1..C5 i8 (per-row scale),
//           Brow[o][5120..7167]=W bf16; scaleC[o]; bias + C0-fold -> bias_aug.
// ============================================================================
__global__ __launch_bounds__(256) void wt_kernel(const float* __restrict__ W,
                                                 const float* __restrict__ C,
                                                 const float* __restrict__ bias,
                                                 char* __restrict__ Brow,
                                                 float* __restrict__ scaleC,
                                                 float* __restrict__ bias_aug) {
    int o   = blockIdx.x;
    int tid = threadIdx.x;
    char* row = Brow + (size_t)o * ROWB;
    float cv[4][5];
    float biasacc = 0.f, amax = 0.f;
    #pragma unroll
    for (int j = 0; j < 4; ++j) {
        int i = tid + j * 256;
        *(unsigned short*)(row + 5120 + i * 2) = f2bf(W[(size_t)o * IN_F + i]);
        const float* c = C + ((size_t)o * IN_F + i) * 6;
        biasacc += c[0];
        #pragma unroll
        for (int k = 0; k < 5; ++k) {
            float v = c[k + 1];
            cv[j][k] = v;
            amax = fmaxf(amax, fabsf(v));
        }
    }
    #pragma unroll
    for (int off = 32; off > 0; off >>= 1) {
        biasacc += __shfl_down(biasacc, off, 64);
        amax = fmaxf(amax, __shfl_down(amax, off, 64));
    }
    __shared__ float redS[4], redM[4];
    int lane = tid & 63, wv = tid >> 6;
    if (lane == 0) { redS[wv] = biasacc; redM[wv] = amax; }
    __syncthreads();
    float rA = fmaxf(fmaxf(redM[0], redM[1]), fmaxf(redM[2], redM[3]));
    rA = fmaxf(rA, 1e-20f);
    float rinv = 127.f / rA;
    if (tid == 0) {
        scaleC[o]   = rA / 127.f;
        bias_aug[o] = bias[o] + redS[0] + redS[1] + redS[2] + redS[3];
    }
    #pragma unroll
    for (int j = 0; j < 4; ++j) {
        int i = tid + j * 256;
        #pragma unroll
        for (int k = 0; k < 5; ++k)
            row[k * 1024 + i] = (char)__float2int_rn(cv[j][k] * rinv);
    }
}

// ============================================================================
// Kernel 3: fused GEMM, 128x128 tile, 4 waves (wave-tile 64x64), grid 512
//   (2 blocks/CU, XCD-local decode). A-operand DIRECT global->VGPR (no LDS,
//   prefetch depth 2, 4 named reg sets); B staged via global_load_lds into
//   4 x 8KB LDS bufs (zero-conflict swizzle). ONE barrier per tile:
//   { stage B(T+3) + load A(T+2) | vmcnt(12) | BAR | rd B(T+1) | lgkm(4) |
//     16 MFMA }.  Tiles 0..79 i8, 80..111 bf16 (uniform addressing).
// ============================================================================
__global__ __launch_bounds__(256, 2) void gemm_kernel(
    const char* __restrict__ Arow,
    const char* __restrict__ Brow,
    const float* __restrict__ scaleC,
    const float* __restrict__ bias_aug,
    float* __restrict__ out)
{
    __shared__ __align__(16) char ldsc[32768];   // 4 x 8KB (B only)

    const int tid  = threadIdx.x;
    const int lane = tid & 63;
    const int wave = tid >> 6;              // 0..3
    const int wr   = wave >> 1;             // 0..1 (M)
    const int wc   = wave & 1;              // 0..1 (N)
    const int fr   = lane & 15;
    const int fg   = lane >> 4;
    const int wrbase = wr * 64;
    const int wcbase = wc * 64;

    // XCD-local decode: bm-sharing blocks stay on one XCD.
    const int bm = (blockIdx.x & 7) * 8 + ((blockIdx.x >> 3) & 7);  // 0..63
    const int bn = blockIdx.x >> 6;                                  // 0..7

    // B staging: dest linear tid*16 per 4KB chunk; source slot inverse-swizzled.
    const int r0   = tid >> 2;
    const int sswz = ((tid & 3) ^ ((tid >> 3) & 3)) << 4;
    const char* gB = Brow + (size_t)(bn * 128 + r0) * ROWB + sswz;

    // B ds_read swizzled slot within 64B row
    const int kcs = (fg << 4) ^ (((fr >> 1) & 3) << 4);

    // A direct per-lane base: lane (fr,fg) reads row (..+fr), bytes fg*16.
    const char* gA = Arow + (size_t)(bm * 128 + wrbase + fr) * ROWB + fg * 16;

    i32x4 accI[4][4] = {};
    f32x4 accF[4][4];
    i32x4 a0[4], a1[4], a2[4], a3[4];   // A frag sets, period 4
    i32x4 bx[4], by[4];                  // B frag sets, period 2

    float sc_[4];
    #pragma unroll
    for (int ni = 0; ni < 4; ++ni)
        sc_[ni] = scaleC[bn * 128 + wcbase + ni * 16 + fr] * (1.f / 63.5f);

#define GLDS(SRC, DST) __builtin_amdgcn_global_load_lds(                        \
    (const __attribute__((address_space(1))) void*)(SRC),                       \
    (__attribute__((address_space(3))) void*)(DST), 16, 0, 0)

#define STAGE_B(S, BO) do {                                                     \
    const size_t _ko = (size_t)(S) * 64;                                        \
    GLDS(gB + _ko,                     ldsc + (BO) + tid * 16);                 \
    GLDS(gB + (size_t)64 * ROWB + _ko, ldsc + (BO) + 4096 + tid * 16);          \
} while (0)

#define LOAD_A(S, DST) do {                                                     \
    _Pragma("unroll")                                                           \
    for (int i_ = 0; i_ < 4; ++i_)                                              \
        DST[i_] = *(const i32x4*)(gA + (size_t)(i_ * 16) * ROWB + (size_t)(S) * 64); \
} while (0)

#define RD_B(DST, BO) do {                                                      \
    _Pragma("unroll")                                                           \
    for (int i_ = 0; i_ < 4; ++i_)                                              \
        DST[i_] = *(const i32x4*)(ldsc + (BO) + (wcbase + i_ * 16 + fr) * 64 + kcs); \
} while (0)

#define MFI(CA, CB) do { __builtin_amdgcn_s_setprio(1);                         \
    _Pragma("unroll")                                                           \
    for (int mi_ = 0; mi_ < 4; ++mi_)                                           \
        _Pragma("unroll")                                                       \
        for (int ni_ = 0; ni_ < 4; ++ni_)                                       \
            accI[mi_][ni_] = __builtin_amdgcn_mfma_i32_16x16x64_i8(             \
                CA[mi_], CB[ni_], accI[mi_][ni_], 0, 0, 0);                     \
    __builtin_amdgcn_s_setprio(0); } while (0)

#define MFF(CA, CB) do { __builtin_amdgcn_s_setprio(1);                         \
    _Pragma("unroll")                                                           \
    for (int mi_ = 0; mi_ < 4; ++mi_)                                           \
        _Pragma("unroll")                                                       \
        for (int ni_ = 0; ni_ < 4; ++ni_)                                       \
            accF[mi_][ni_] = __builtin_amdgcn_mfma_f32_16x16x32_bf16(           \
                __builtin_bit_cast(bf16x8, CA[mi_]),                            \
                __builtin_bit_cast(bf16x8, CB[ni_]),                            \
                accF[mi_][ni_], 0, 0, 0);                                       \
    __builtin_amdgcn_s_setprio(0); } while (0)

// One tile: MFMA(T) from AU (loaded T-2) and BU (read T-1); read B(T+1);
// stage B(T+3); load A(T+2).
#define TILE(T, AU, AL, BU, BNX, BUFN, BUFS, MF, DOST, DOA, RDN, CNT, LG) do {  \
    if (DOST) STAGE_B((T) + 3, (BUFS));                                         \
    if (DOA)  LOAD_A((T) + 2, AL);                                              \
    __builtin_amdgcn_sched_barrier(0);                                          \
    asm volatile("s_waitcnt vmcnt(" #CNT ")" ::: "memory");                     \
    __builtin_amdgcn_s_barrier();                                               \
    if (RDN) RD_B(BNX, (BUFN));                                                 \
    asm volatile("s_waitcnt lgkmcnt(" #LG ")" ::: "memory");                    \
    __builtin_amdgcn_sched_barrier(0);                                          \
    MF(AU, BU);                                                                 \
} while (0)

    // prologue: stage B0..B2, load A0,A1; B0..B2+A0 landed; read B(0)->bx.
    STAGE_B(0, 0 * BUF);
    STAGE_B(1, 1 * BUF);
    STAGE_B(2, 2 * BUF);
    LOAD_A(0, a0);
    LOAD_A(1, a1);
    __builtin_amdgcn_sched_barrier(0);
    asm volatile("s_waitcnt vmcnt(4)" ::: "memory");
    __builtin_amdgcn_s_barrier();
    RD_B(bx, 0 * BUF);

    // i8 segment: tiles 0..79 (stage/load run ahead into bf16 region)
    for (int t = 0; t < 80; t += 4) {
        TILE(t + 0, a0, a2, bx, by, 1 * BUF, 3 * BUF, MFI, 1, 1, 1, 12, 4);
        TILE(t + 1, a1, a3, by, bx, 2 * BUF, 0 * BUF, MFI, 1, 1, 1, 12, 4);
        TILE(t + 2, a2, a0, bx, by, 3 * BUF, 1 * BUF, MFI, 1, 1, 1, 12, 4);
        TILE(t + 3, a3, a1, by, bx, 0 * BUF, 2 * BUF, MFI, 1, 1, 1, 12, 4);
    }

    // dequantize: accF = accI * scaleC[col]/63.5
    #pragma unroll
    for (int mi = 0; mi < 4; ++mi)
        #pragma unroll
        for (int ni = 0; ni < 4; ++ni)
            #pragma unroll
            for (int rr = 0; rr < 4; ++rr)
                accF[mi][ni][rr] = (float)accI[mi][ni][rr] * sc_[ni];

    // bf16 segment: tiles 80..107
    for (int t = 80; t < 108; t += 4) {
        TILE(t + 0, a0, a2, bx, by, 1 * BUF, 3 * BUF, MFF, 1, 1, 1, 12, 4);
        TILE(t + 1, a1, a3, by, bx, 2 * BUF, 0 * BUF, MFF, 1, 1, 1, 12, 4);
        TILE(t + 2, a2, a0, bx, by, 3 * BUF, 1 * BUF, MFF, 1, 1, 1, 12, 4);
        TILE(t + 3, a3, a1, by, bx, 0 * BUF, 2 * BUF, MFF, 1, 1, 1, 12, 4);
    }
    // tail: 108..111
    TILE(108, a0, a2, bx, by, 1 * BUF, 3 * BUF, MFF, 1, 1, 1, 12, 4);
    TILE(109, a1, a3, by, bx, 2 * BUF, 0 * BUF, MFF, 0, 1, 1, 10, 4);
    TILE(110, a2, a0, bx, by, 3 * BUF, 1 * BUF, MFF, 0, 0, 1,  4, 4);
    TILE(111, a3, a1, by, bx, 0 * BUF, 2 * BUF, MFF, 0, 0, 0,  0, 0);

#undef TILE
#undef MFF
#undef MFI
#undef RD_B
#undef LOAD_A
#undef STAGE_B
#undef GLDS

    // epilogue: D row=(lane>>4)*4+reg, col=lane&15 ; + bias
    #pragma unroll
    for (int ni = 0; ni < 4; ++ni) {
        const int col = bn * 128 + wcbase + ni * 16 + fr;
        const float bv = bias_aug[col];
        #pragma unroll
        for (int mi = 0; mi < 4; ++mi) {
            #pragma unroll
            for (int rr = 0; rr < 4; ++rr) {
                const int row = bm * 128 + wrbase + mi * 16 + fg * 4 + rr;
                out[(size_t)row * OUT_F + col] = accF[mi][ni][rr] + bv;
            }
        }
    }
}

// ============================================================================
extern "C" void kernel_launch(void* const* d_in, const int* in_sizes, int n_in,
                              void* d_out, int out_size, void* d_ws, size_t ws_size,
                              hipStream_t stream) {
    const float* x    = (const float*)d_in[0];
    const float* W    = (const float*)d_in[1];
    const float* C    = (const float*)d_in[2];
    const float* bias = (const float*)d_in[3];
    float* out = (float*)d_out;

    char* ws = (char*)d_ws;
    char*  Arow     = ws;                               // 8192*7168 = 58,720,256
    char*  Brow     = ws + 58720256;                    // 1024*7168 =  7,340,032
    float* bias_aug = (float*)(ws + 66060288);          // 4 KB
    float* scaleC   = (float*)(ws + 66064384);          // 4 KB

    hipLaunchKernelGGL(act_kernel, dim3(TOKENS * IN_F / 8 / 256), dim3(256), 0, stream,
                       x, Arow);
    hipLaunchKernelGGL(wt_kernel, dim3(OUT_F), dim3(256), 0, stream,
                       W, C, bias, Brow, scaleC, bias_aug);
    hipLaunchKernelGGL(gemm_kernel, dim3(512), dim3(256), 0, stream,
                       Arow, Brow, scaleC, bias_aug, out);
}

// Round 13
// 126.209 us; speedup vs baseline: 1.1962x; 1.1962x over previous
//
#include <hip/hip_runtime.h>
#include <hip/hip_bf16.h>
#include <cstdint>
#include <cstddef>

#define TOKENS 8192
#define IN_F   1024
#define OUT_F  1024
#define ROWB   7168          // row stride bytes: 5120 i8 (P1..P5) + 2048 bf16 (silu)
#define BUF0   0
#define BUF1   12288
#define BUF2   24576
#define BUF3   36864

typedef __attribute__((ext_vector_type(4))) float          f32x4;
typedef __attribute__((ext_vector_type(4))) float          float4v;
typedef __attribute__((ext_vector_type(4))) int            i32x4;
typedef __attribute__((ext_vector_type(8))) __bf16         bf16x8;
typedef __attribute__((ext_vector_type(8))) unsigned short ushort8;
typedef __attribute__((ext_vector_type(8))) char           char8;

__device__ __forceinline__ unsigned short f2bf(float f) {
    unsigned int u = __builtin_bit_cast(unsigned int, f);
    u += 0x7FFFu + ((u >> 16) & 1u);
    return (unsigned short)(u >> 16);
}

// ============================================================================
// Kernel 1: activations -> interleaved rows Arow[b][0..5119]=P1..P5 i8 (x63.5),
//           Arow[b][5120..7167] = silu bf16.  Fast tanh via __expf.
// ============================================================================
__global__ __launch_bounds__(256) void act_kernel(const float* __restrict__ x,
                                                  char* __restrict__ Arow) {
    int gid = blockIdx.x * 256 + threadIdx.x;
    int b   = gid >> 7;
    int i8  = (gid & 127) << 3;

    const float* xp = x + (size_t)b * IN_F + i8;
    float xs[8];
    *(float4v*)&xs[0] = *(const float4v*)xp;
    *(float4v*)&xs[4] = *(const float4v*)(xp + 4);

    unsigned short sres[8];
    char8 q[5];
    #pragma unroll
    for (int e = 0; e < 8; ++e) {
        float v  = xs[e];
        float s  = v / (1.f + __expf(-v));
        float t  = 1.f - 2.f / (1.f + __expf(2.f * v));   // tanh(v), exact at +-inf
        float p1 = 2.f * t;
        float p2 = (12.f / 24.f) * t * p1 - (8.f / 24.f) * 1.f;
        float p3 = (64.f / 120.f) * t * p2 - (48.f / 120.f) * p1;
        float p4 = (180.f / 336.f) * t * p3 - (144.f / 336.f) * p2;
        float p5 = (384.f / 720.f) * t * p4 - (320.f / 720.f) * p3;
        sres[e] = f2bf(s);
        q[0][e] = (char)__float2int_rn(p1 * 63.5f);
        q[1][e] = (char)__float2int_rn(p2 * 63.5f);
        q[2][e] = (char)__float2int_rn(p3 * 63.5f);
        q[3][e] = (char)__float2int_rn(p4 * 63.5f);
        q[4][e] = (char)__float2int_rn(p5 * 63.5f);
    }
    char* row = Arow + (size_t)b * ROWB;
    #pragma unroll
    for (int k = 0; k < 5; ++k)
        *(char8*)(row + k * 1024 + i8) = q[k];
    *(ushort8*)(row + 5120 + i8 * 2) = *(const ushort8*)&sres[0];
}

// ============================================================================
// Kernel 2: weights -> Brow[o][0..5119]=C1..C5 i8 (per-row scale),
//           Brow[o][5120..7167]=W bf16; scaleC[o]; bias + C0-fold -> bias_aug.
// ============================================================================
__global__ __launch_bounds__(256) void wt_kernel(const float* __restrict__ W,
                                                 const float* __restrict__ C,
                                                 const float* __restrict__ bias,
                                                 char* __restrict__ Brow,
                                                 float* __restrict__ scaleC,
                                                 float* __restrict__ bias_aug) {
    int o   = blockIdx.x;
    int tid = threadIdx.x;
    char* row = Brow + (size_t)o * ROWB;
    float cv[4][5];
    float biasacc = 0.f, amax = 0.f;
    #pragma unroll
    for (int j = 0; j < 4; ++j) {
        int i = tid + j * 256;
        *(unsigned short*)(row + 5120 + i * 2) = f2bf(W[(size_t)o * IN_F + i]);
        const float* c = C + ((size_t)o * IN_F + i) * 6;
        biasacc += c[0];
        #pragma unroll
        for (int k = 0; k < 5; ++k) {
            float v = c[k + 1];
            cv[j][k] = v;
            amax = fmaxf(amax, fabsf(v));
        }
    }
    #pragma unroll
    for (int off = 32; off > 0; off >>= 1) {
        biasacc += __shfl_down(biasacc, off, 64);
        amax = fmaxf(amax, __shfl_down(amax, off, 64));
    }
    __shared__ float redS[4], redM[4];
    int lane = tid & 63, wv = tid >> 6;
    if (lane == 0) { redS[wv] = biasacc; redM[wv] = amax; }
    __syncthreads();
    float rA = fmaxf(fmaxf(redM[0], redM[1]), fmaxf(redM[2], redM[3]));
    rA = fmaxf(rA, 1e-20f);
    float rinv = 127.f / rA;
    if (tid == 0) {
        scaleC[o]   = rA / 127.f;
        bias_aug[o] = bias[o] + redS[0] + redS[1] + redS[2] + redS[3];
    }
    #pragma unroll
    for (int j = 0; j < 4; ++j) {
        int i = tid + j * 256;
        #pragma unroll
        for (int k = 0; k < 5; ++k)
            row[k * 1024 + i] = (char)__float2int_rn(cv[j][k] * rinv);
    }
}

// ============================================================================
// Kernel 3: fused GEMM, 128x64 tile, 4 waves (wave-tile 64x32), grid 1024,
//   launch_bounds(256,3): 3 blocks/CU (3 waves/SIMD), VGPR cap ~170 (no spill
//   -> counted vmcnt stays sound). XCD-local decode. LDS 48KB = 4 bufs x
//   [A 128x64B | B 64x64B], zero-conflict XOR swizzle. Round-9-proven
//   depth-3 / 4-buffer / 2-barrier schedule (counts scaled to 3-load stages):
//     STAGE(T+3) | vmcnt(6) | BAR1 | RD(T+1) | lgkm(6) | 8 MFMA | BAR2
//   Tiles 0..79 i8 (mfma_i32_16x16x64_i8), 80..111 bf16; separate accI/accF.
// ============================================================================
__global__ __launch_bounds__(256, 3) void gemm_kernel(
    const char* __restrict__ Arow,
    const char* __restrict__ Brow,
    const float* __restrict__ scaleC,
    const float* __restrict__ bias_aug,
    float* __restrict__ out)
{
    __shared__ __align__(16) char ldsc[49152];   // 4 x 12KB

    const int tid  = threadIdx.x;
    const int lane = tid & 63;
    const int wave = tid >> 6;              // 0..3
    const int wr   = wave >> 1;             // 0..1 (M)
    const int wc   = wave & 1;              // 0..1 (N)
    const int fr   = lane & 15;
    const int fg   = lane >> 4;
    const int wrbase = wr * 64;
    const int wcbase = wc * 32;

    // XCD-local decode (bijective): each XCD owns 8 bm panels x all 16 bn.
    const int bm = (blockIdx.x & 7) * 8 + ((blockIdx.x >> 3) & 7);  // 0..63
    const int bn = blockIdx.x >> 6;                                  // 0..15

    // staging: dest linear tid*16 per 4KB chunk (64 rows x 64B);
    // dest row r = chunk*64 + (tid>>2), slot tid&3;
    // source slot = (tid&3) ^ ((r>>1)&3) = (tid&3) ^ ((tid>>3)&3).
    const int r0   = tid >> 2;
    const int sswz = ((tid & 3) ^ ((tid >> 3) & 3)) << 4;
    const char* gA = Arow + (size_t)(bm * 128 + r0) * ROWB + sswz;
    const char* gB = Brow + (size_t)(bn * 64 + r0) * ROWB + sswz;

    // ds_read swizzled slot within 64B row ((row>>1)&3 == (fr>>1)&3)
    const int kcs = (fg << 4) ^ (((fr >> 1) & 3) << 4);

    i32x4 accI[4][2] = {};
    f32x4 accF[4][2];
    i32x4 xa[4], xb[2], ya[4], yb[2];

    float sc_[2];
    #pragma unroll
    for (int ni = 0; ni < 2; ++ni)
        sc_[ni] = scaleC[bn * 64 + wcbase + ni * 16 + fr] * (1.f / 63.5f);

#define GLDS(SRC, DST) __builtin_amdgcn_global_load_lds(                        \
    (const __attribute__((address_space(1))) void*)(SRC),                       \
    (__attribute__((address_space(3))) void*)(DST), 16, 0, 0)

#define STAGE(S, BO) do {                                                       \
    const size_t _ko = (size_t)(S) * 64;                                        \
    GLDS(gA + _ko,                     ldsc + (BO) + tid * 16);                 \
    GLDS(gA + (size_t)64 * ROWB + _ko, ldsc + (BO) + 4096 + tid * 16);          \
    GLDS(gB + _ko,                     ldsc + (BO) + 8192 + tid * 16);          \
} while (0)

#define RD(DA, DB, BO) do {                                                     \
    _Pragma("unroll")                                                           \
    for (int i_ = 0; i_ < 4; ++i_)                                              \
        DA[i_] = *(const i32x4*)(ldsc + (BO) + (wrbase + i_ * 16 + fr) * 64 + kcs); \
    _Pragma("unroll")                                                           \
    for (int i_ = 0; i_ < 2; ++i_)                                              \
        DB[i_] = *(const i32x4*)(ldsc + (BO) + 8192 + (wcbase + i_ * 16 + fr) * 64 + kcs); \
} while (0)

#define MFI(CA, CB) do { __builtin_amdgcn_s_setprio(1);                         \
    _Pragma("unroll")                                                           \
    for (int mi_ = 0; mi_ < 4; ++mi_)                                           \
        _Pragma("unroll")                                                       \
        for (int ni_ = 0; ni_ < 2; ++ni_)                                       \
            accI[mi_][ni_] = __builtin_amdgcn_mfma_i32_16x16x64_i8(             \
                CA[mi_], CB[ni_], accI[mi_][ni_], 0, 0, 0);                     \
    __builtin_amdgcn_s_setprio(0); } while (0)

#define MFF(CA, CB) do { __builtin_amdgcn_s_setprio(1);                         \
    _Pragma("unroll")                                                           \
    for (int mi_ = 0; mi_ < 4; ++mi_)                                           \
        _Pragma("unroll")                                                       \
        for (int ni_ = 0; ni_ < 2; ++ni_)                                       \
            accF[mi_][ni_] = __builtin_amdgcn_mfma_f32_16x16x32_bf16(           \
                __builtin_bit_cast(bf16x8, CA[mi_]),                            \
                __builtin_bit_cast(bf16x8, CB[ni_]),                            \
                accF[mi_][ni_], 0, 0, 0);                                       \
    __builtin_amdgcn_s_setprio(0); } while (0)

// tile T: MFMA(T) from (CA,CB) [read at T-1]; read frags T+1; stage T+3.
#define TILE(T, MF, CA, CB, NA, NB, BUFN, BUFS, DOST, RDN, CNT, LG) do {        \
    if (DOST) STAGE((T) + 3, (BUFS));                                           \
    __builtin_amdgcn_sched_barrier(0);                                          \
    asm volatile("s_waitcnt vmcnt(" #CNT ")" ::: "memory");                     \
    __builtin_amdgcn_s_barrier();                                               \
    if (RDN) RD(NA, NB, (BUFN));                                                \
    asm volatile("s_waitcnt lgkmcnt(" #LG ")" ::: "memory");                    \
    __builtin_amdgcn_sched_barrier(0);                                          \
    MF(CA, CB);                                                                 \
    __builtin_amdgcn_s_barrier();                                               \
} while (0)

#define GROUP4(T, MF) do {                                                      \
    TILE((T) + 0, MF, xa, xb, ya, yb, BUF1, BUF3, 1, 1, 6, 6);                  \
    TILE((T) + 1, MF, ya, yb, xa, xb, BUF2, BUF0, 1, 1, 6, 6);                  \
    TILE((T) + 2, MF, xa, xb, ya, yb, BUF3, BUF1, 1, 1, 6, 6);                  \
    TILE((T) + 3, MF, ya, yb, xa, xb, BUF0, BUF2, 1, 1, 6, 6);                  \
} while (0)

    // prologue: stage tiles 0,1,2; stage(0) landed (6 younger in flight);
    // BAR -> cross-wave; pre-read tile-0 frags.
    STAGE(0, BUF0);
    STAGE(1, BUF1);
    STAGE(2, BUF2);
    __builtin_amdgcn_sched_barrier(0);
    asm volatile("s_waitcnt vmcnt(6)" ::: "memory");
    __builtin_amdgcn_s_barrier();
    RD(xa, xb, BUF0);

    // i8 segment: tiles 0..79 (20 groups of 4; staging runs ahead uniformly)
    for (int t = 0; t < 80; t += 4) GROUP4(t, MFI);

    // dequantize: accF = accI * scaleC[col]/63.5
    #pragma unroll
    for (int mi = 0; mi < 4; ++mi)
        #pragma unroll
        for (int ni = 0; ni < 2; ++ni)
            #pragma unroll
            for (int rr = 0; rr < 4; ++rr)
                accF[mi][ni][rr] = (float)accI[mi][ni][rr] * sc_[ni];

    // bf16 segment: tiles 80..107 (7 groups), tail 108..111
    for (int t = 80; t < 108; t += 4) GROUP4(t, MFF);
    TILE(108, MFF, xa, xb, ya, yb, BUF1, BUF3, 1, 1, 6, 6);
    TILE(109, MFF, ya, yb, xa, xb, BUF2, BUF0, 0, 1, 3, 6);
    TILE(110, MFF, xa, xb, ya, yb, BUF3, BUF0, 0, 1, 0, 6);
    TILE(111, MFF, ya, yb, xa, xb, BUF0, BUF0, 0, 0, 0, 0);

#undef GROUP4
#undef TILE
#undef MFF
#undef MFI
#undef RD
#undef STAGE
#undef GLDS

    // epilogue: D row=(lane>>4)*4+reg, col=lane&15 ; + bias
    #pragma unroll
    for (int ni = 0; ni < 2; ++ni) {
        const int col = bn * 64 + wcbase + ni * 16 + fr;
        const float bv = bias_aug[col];
        #pragma unroll
        for (int mi = 0; mi < 4; ++mi) {
            #pragma unroll
            for (int rr = 0; rr < 4; ++rr) {
                const int row = bm * 128 + wrbase + mi * 16 + fg * 4 + rr;
                out[(size_t)row * OUT_F + col] = accF[mi][ni][rr] + bv;
            }
        }
    }
}

// ============================================================================
extern "C" void kernel_launch(void* const* d_in, const int* in_sizes, int n_in,
                              void* d_out, int out_size, void* d_ws, size_t ws_size,
                              hipStream_t stream) {
    const float* x    = (const float*)d_in[0];
    const float* W    = (const float*)d_in[1];
    const float* C    = (const float*)d_in[2];
    const float* bias = (const float*)d_in[3];
    float* out = (float*)d_out;

    char* ws = (char*)d_ws;
    char*  Arow     = ws;                               // 8192*7168 = 58,720,256
    char*  Brow     = ws + 58720256;                    // 1024*7168 =  7,340,032
    float* bias_aug = (float*)(ws + 66060288);          // 4 KB
    float* scaleC   = (float*)(ws + 66064384);          // 4 KB

    hipLaunchKernelGGL(act_kernel, dim3(TOKENS * IN_F / 8 / 256), dim3(256), 0, stream,
                       x, Arow);
    hipLaunchKernelGGL(wt_kernel, dim3(OUT_F), dim3(256), 0, stream,
                       W, C, bias, Brow, scaleC, bias_aug);
    hipLaunchKernelGGL(gemm_kernel, dim3(1024), dim3(256), 0, stream,
                       Arow, Brow, scaleC, bias_aug, out);
}

// Round 14
// 103.204 us; speedup vs baseline: 1.4628x; 1.2229x over previous
//
#include <hip/hip_runtime.h>
#include <hip/hip_bf16.h>
#include <cstdint>
#include <cstddef>

#define TOKENS 8192
#define IN_F   1024
#define OUT_F  1024
#define ROWB   7168          // row stride bytes: 5120 i8 (P1..P5) + 2048 bf16 (silu)
#define B0     0
#define B1     16384
#define B2     32768
#define B3     49152
#define B4     65536

typedef __attribute__((ext_vector_type(4))) float          f32x4;
typedef __attribute__((ext_vector_type(4))) float          float4v;
typedef __attribute__((ext_vector_type(4))) int            i32x4;
typedef __attribute__((ext_vector_type(8))) __bf16         bf16x8;
typedef __attribute__((ext_vector_type(8))) unsigned short ushort8;
typedef __attribute__((ext_vector_type(8))) char           char8;

__device__ __forceinline__ unsigned short f2bf(float f) {
    unsigned int u = __builtin_bit_cast(unsigned int, f);
    u += 0x7FFFu + ((u >> 16) & 1u);
    return (unsigned short)(u >> 16);
}

// ============================================================================
// Kernel 1: activations -> interleaved rows Arow[b][0..5119]=P1..P5 i8 (x63.5),
//           Arow[b][5120..7167] = silu bf16.  Fast tanh via __expf.
// ============================================================================
__global__ __launch_bounds__(256) void act_kernel(const float* __restrict__ x,
                                                  char* __restrict__ Arow) {
    int gid = blockIdx.x * 256 + threadIdx.x;
    int b   = gid >> 7;
    int i8  = (gid & 127) << 3;

    const float* xp = x + (size_t)b * IN_F + i8;
    float xs[8];
    *(float4v*)&xs[0] = *(const float4v*)xp;
    *(float4v*)&xs[4] = *(const float4v*)(xp + 4);

    unsigned short sres[8];
    char8 q[5];
    #pragma unroll
    for (int e = 0; e < 8; ++e) {
        float v  = xs[e];
        float s  = v / (1.f + __expf(-v));
        float t  = 1.f - 2.f / (1.f + __expf(2.f * v));   // tanh(v), exact at +-inf
        float p1 = 2.f * t;
        float p2 = (12.f / 24.f) * t * p1 - (8.f / 24.f) * 1.f;
        float p3 = (64.f / 120.f) * t * p2 - (48.f / 120.f) * p1;
        float p4 = (180.f / 336.f) * t * p3 - (144.f / 336.f) * p2;
        float p5 = (384.f / 720.f) * t * p4 - (320.f / 720.f) * p3;
        sres[e] = f2bf(s);
        q[0][e] = (char)__float2int_rn(p1 * 63.5f);
        q[1][e] = (char)__float2int_rn(p2 * 63.5f);
        q[2][e] = (char)__float2int_rn(p3 * 63.5f);
        q[3][e] = (char)__float2int_rn(p4 * 63.5f);
        q[4][e] = (char)__float2int_rn(p5 * 63.5f);
    }
    char* row = Arow + (size_t)b * ROWB;
    #pragma unroll
    for (int k = 0; k < 5; ++k)
        *(char8*)(row + k * 1024 + i8) = q[k];
    *(ushort8*)(row + 5120 + i8 * 2) = *(const ushort8*)&sres[0];
}

// ============================================================================
// Kernel 2: weights -> Brow[o][0..5119]=C1..C5 i8 (per-row scale),
//           Brow[o][5120..7167]=W bf16; scaleC[o]; bias + C0-fold -> bias_aug.
// ============================================================================
__global__ __launch_bounds__(256) void wt_kernel(const float* __restrict__ W,
                                                 const float* __restrict__ C,
                                                 const float* __restrict__ bias,
                                                 char* __restrict__ Brow,
                                                 float* __restrict__ scaleC,
                                                 float* __restrict__ bias_aug) {
    int o   = blockIdx.x;
    int tid = threadIdx.x;
    char* row = Brow + (size_t)o * ROWB;
    float cv[4][5];
    float biasacc = 0.f, amax = 0.f;
    #pragma unroll
    for (int j = 0; j < 4; ++j) {
        int i = tid + j * 256;
        *(unsigned short*)(row + 5120 + i * 2) = f2bf(W[(size_t)o * IN_F + i]);
        const float* c = C + ((size_t)o * IN_F + i) * 6;
        biasacc += c[0];
        #pragma unroll
        for (int k = 0; k < 5; ++k) {
            float v = c[k + 1];
            cv[j][k] = v;
            amax = fmaxf(amax, fabsf(v));
        }
    }
    #pragma unroll
    for (int off = 32; off > 0; off >>= 1) {
        biasacc += __shfl_down(biasacc, off, 64);
        amax = fmaxf(amax, __shfl_down(amax, off, 64));
    }
    __shared__ float redS[4], redM[4];
    int lane = tid & 63, wv = tid >> 6;
    if (lane == 0) { redS[wv] = biasacc; redM[wv] = amax; }
    __syncthreads();
    float rA = fmaxf(fmaxf(redM[0], redM[1]), fmaxf(redM[2], redM[3]));
    rA = fmaxf(rA, 1e-20f);
    float rinv = 127.f / rA;
    if (tid == 0) {
        scaleC[o]   = rA / 127.f;
        bias_aug[o] = bias[o] + redS[0] + redS[1] + redS[2] + redS[3];
    }
    #pragma unroll
    for (int j = 0; j < 4; ++j) {
        int i = tid + j * 256;
        #pragma unroll
        for (int k = 0; k < 5; ++k)
            row[k * 1024 + i] = (char)__float2int_rn(cv[j][k] * rinv);
    }
}

// ============================================================================
// Kernel 3: fused GEMM — round-9 geometry (128x128 tile, 4 waves, wave-tile
//   64x64, grid 512 = 2 blocks/CU, XCD-local decode), but FIVE 16KB LDS bufs
//   and ONE barrier per tile:
//     STAGE(T+3) | vmcnt(8) | BAR | RD(T+1) | lgkm(8) | 16 MFMA
//   WAR proof: stage@T hits buf (T-2)%5; its readers retired at the lgkm
//   gate inside tile T-2, which precedes BAR@(T-1); writer's stage@T follows
//   BAR@(T-1).  (4 bufs would need the trailing barrier round 9 had.)
//   Tiles 0..79 i8 (mfma_i32_16x16x64_i8), 80..111 bf16.
// ============================================================================
__global__ __launch_bounds__(256, 2) void gemm_kernel(
    const char* __restrict__ Arow,
    const char* __restrict__ Brow,
    const float* __restrict__ scaleC,
    const float* __restrict__ bias_aug,
    float* __restrict__ out)
{
    __shared__ __align__(16) char ldsc[81920];   // 5 x 16KB

    const int tid  = threadIdx.x;
    const int lane = tid & 63;
    const int wave = tid >> 6;              // 0..3
    const int wr   = wave >> 1;             // 0..1 (M)
    const int wc   = wave & 1;              // 0..1 (N)
    const int fr   = lane & 15;
    const int fg   = lane >> 4;
    const int wrbase = wr * 64;
    const int wcbase = wc * 64;

    // XCD-local decode: bm-sharing blocks stay on one XCD (A fetched once).
    const int bm = (blockIdx.x & 7) * 8 + ((blockIdx.x >> 3) & 7);  // 0..63
    const int bn = blockIdx.x >> 6;                                  // 0..7

    // staging: dest linear tid*16 per 4KB chunk (64 rows x 64B);
    // source slot = (tid&3) ^ ((tid>>3)&3) (inverse of read swizzle).
    const int r0   = tid >> 2;
    const int sswz = ((tid & 3) ^ ((tid >> 3) & 3)) << 4;
    const char* gA = Arow + (size_t)(bm * 128 + r0) * ROWB + sswz;
    const char* gB = Brow + (size_t)(bn * 128 + r0) * ROWB + sswz;

    // ds_read swizzled slot within 64B row ((row>>1)&3 == (fr>>1)&3)
    const int kcs = (fg << 4) ^ (((fr >> 1) & 3) << 4);

    i32x4 accI[4][4] = {};
    f32x4 accF[4][4];
    i32x4 xa[4], xb[4], ya[4], yb[4];

    float sc_[4];
    #pragma unroll
    for (int ni = 0; ni < 4; ++ni)
        sc_[ni] = scaleC[bn * 128 + wcbase + ni * 16 + fr] * (1.f / 63.5f);

#define GLDS(SRC, DST) __builtin_amdgcn_global_load_lds(                        \
    (const __attribute__((address_space(1))) void*)(SRC),                       \
    (__attribute__((address_space(3))) void*)(DST), 16, 0, 0)

#define STAGE(S, BO) do {                                                       \
    const size_t _ko = (size_t)(S) * 64;                                        \
    GLDS(gA + _ko,                     ldsc + (BO) + tid * 16);                 \
    GLDS(gA + (size_t)64 * ROWB + _ko, ldsc + (BO) + 4096 + tid * 16);          \
    GLDS(gB + _ko,                     ldsc + (BO) + 8192 + tid * 16);          \
    GLDS(gB + (size_t)64 * ROWB + _ko, ldsc + (BO) + 12288 + tid * 16);         \
} while (0)

#define RD(DA, DB, BO) do {                                                     \
    _Pragma("unroll")                                                           \
    for (int i_ = 0; i_ < 4; ++i_)                                              \
        DA[i_] = *(const i32x4*)(ldsc + (BO) + (wrbase + i_ * 16 + fr) * 64 + kcs); \
    _Pragma("unroll")                                                           \
    for (int i_ = 0; i_ < 4; ++i_)                                              \
        DB[i_] = *(const i32x4*)(ldsc + (BO) + 8192 + (wcbase + i_ * 16 + fr) * 64 + kcs); \
} while (0)

#define MFI(CA, CB) do { __builtin_amdgcn_s_setprio(1);                         \
    _Pragma("unroll")                                                           \
    for (int mi_ = 0; mi_ < 4; ++mi_)                                           \
        _Pragma("unroll")                                                       \
        for (int ni_ = 0; ni_ < 4; ++ni_)                                       \
            accI[mi_][ni_] = __builtin_amdgcn_mfma_i32_16x16x64_i8(             \
                CA[mi_], CB[ni_], accI[mi_][ni_], 0, 0, 0);                     \
    __builtin_amdgcn_s_setprio(0); } while (0)

#define MFF(CA, CB) do { __builtin_amdgcn_s_setprio(1);                         \
    _Pragma("unroll")                                                           \
    for (int mi_ = 0; mi_ < 4; ++mi_)                                           \
        _Pragma("unroll")                                                       \
        for (int ni_ = 0; ni_ < 4; ++ni_)                                       \
            accF[mi_][ni_] = __builtin_amdgcn_mfma_f32_16x16x32_bf16(           \
                __builtin_bit_cast(bf16x8, CA[mi_]),                            \
                __builtin_bit_cast(bf16x8, CB[ni_]),                            \
                accF[mi_][ni_], 0, 0, 0);                                       \
    __builtin_amdgcn_s_setprio(0); } while (0)

// tile T: MFMA(T) from (CA,CB) [read at T-1]; read frags T+1 from RDB;
// stage T+3 into STB.  ONE barrier.
#define TILE(T, MF, CA, CB, NA, NB, RDB, STB, DOST, RDN, CNT, LG) do {          \
    if (DOST) STAGE((T) + 3, (STB));                                            \
    __builtin_amdgcn_sched_barrier(0);                                          \
    asm volatile("s_waitcnt vmcnt(" #CNT ")" ::: "memory");                     \
    __builtin_amdgcn_s_barrier();                                               \
    if (RDN) RD(NA, NB, (RDB));                                                 \
    asm volatile("s_waitcnt lgkmcnt(" #LG ")" ::: "memory");                    \
    __builtin_amdgcn_sched_barrier(0);                                          \
    MF(CA, CB);                                                                 \
} while (0)

// 10-tile group: buf period 5 x frag ping-pong 2.  T must be ≡ 0 (mod 10).
#define GROUP10(T, MF) do {                                                     \
    TILE((T) + 0, MF, xa, xb, ya, yb, B1, B3, 1, 1, 8, 8);                      \
    TILE((T) + 1, MF, ya, yb, xa, xb, B2, B4, 1, 1, 8, 8);                      \
    TILE((T) + 2, MF, xa, xb, ya, yb, B3, B0, 1, 1, 8, 8);                      \
    TILE((T) + 3, MF, ya, yb, xa, xb, B4, B1, 1, 1, 8, 8);                      \
    TILE((T) + 4, MF, xa, xb, ya, yb, B0, B2, 1, 1, 8, 8);                      \
    TILE((T) + 5, MF, ya, yb, xa, xb, B1, B3, 1, 1, 8, 8);                      \
    TILE((T) + 6, MF, xa, xb, ya, yb, B2, B4, 1, 1, 8, 8);                      \
    TILE((T) + 7, MF, ya, yb, xa, xb, B3, B0, 1, 1, 8, 8);                      \
    TILE((T) + 8, MF, xa, xb, ya, yb, B4, B1, 1, 1, 8, 8);                      \
    TILE((T) + 9, MF, ya, yb, xa, xb, B0, B2, 1, 1, 8, 8);                      \
} while (0)

    // prologue: stage tiles 0,1,2 -> bufs 0,1,2; tile-0 landed (allow 8
    // younger); BAR -> cross-wave; pre-read tile-0 frags.
    STAGE(0, B0);
    STAGE(1, B1);
    STAGE(2, B2);
    __builtin_amdgcn_sched_barrier(0);
    asm volatile("s_waitcnt vmcnt(8)" ::: "memory");
    __builtin_amdgcn_s_barrier();
    RD(xa, xb, B0);

    // i8 segment: tiles 0..79 (8 groups of 10)
    for (int t = 0; t < 80; t += 10) GROUP10(t, MFI);

    // dequantize: accF = accI * scaleC[col]/63.5
    #pragma unroll
    for (int mi = 0; mi < 4; ++mi)
        #pragma unroll
        for (int ni = 0; ni < 4; ++ni)
            #pragma unroll
            for (int rr = 0; rr < 4; ++rr)
                accF[mi][ni][rr] = (float)accI[mi][ni][rr] * sc_[ni];

    // bf16 segment: tiles 80..99 (2 groups), then 100..111 explicit tail
    GROUP10(80, MFF);
    GROUP10(90, MFF);
    TILE(100, MFF, xa, xb, ya, yb, B1, B3, 1, 1, 8, 8);
    TILE(101, MFF, ya, yb, xa, xb, B2, B4, 1, 1, 8, 8);
    TILE(102, MFF, xa, xb, ya, yb, B3, B0, 1, 1, 8, 8);
    TILE(103, MFF, ya, yb, xa, xb, B4, B1, 1, 1, 8, 8);
    TILE(104, MFF, xa, xb, ya, yb, B0, B2, 1, 1, 8, 8);
    TILE(105, MFF, ya, yb, xa, xb, B1, B3, 1, 1, 8, 8);
    TILE(106, MFF, xa, xb, ya, yb, B2, B4, 1, 1, 8, 8);
    TILE(107, MFF, ya, yb, xa, xb, B3, B0, 1, 1, 8, 8);
    TILE(108, MFF, xa, xb, ya, yb, B4, B1, 1, 1, 8, 8);   // stages 111 -> B1
    TILE(109, MFF, ya, yb, xa, xb, B0, B0, 0, 1, 4, 8);   // rd 110 (buf 0)
    TILE(110, MFF, xa, xb, ya, yb, B1, B0, 0, 1, 0, 8);   // rd 111 (buf 1)
    TILE(111, MFF, ya, yb, xa, xb, B0, B0, 0, 0, 0, 0);

#undef GROUP10
#undef TILE
#undef MFF
#undef MFI
#undef RD
#undef STAGE
#undef GLDS

    // epilogue: D row=(lane>>4)*4+reg, col=lane&15 ; + bias
    #pragma unroll
    for (int ni = 0; ni < 4; ++ni) {
        const int col = bn * 128 + wcbase + ni * 16 + fr;
        const float bv = bias_aug[col];
        #pragma unroll
        for (int mi = 0; mi < 4; ++mi) {
            #pragma unroll
            for (int rr = 0; rr < 4; ++rr) {
                const int row = bm * 128 + wrbase + mi * 16 + fg * 4 + rr;
                out[(size_t)row * OUT_F + col] = accF[mi][ni][rr] + bv;
            }
        }
    }
}

// ============================================================================
extern "C" void kernel_launch(void* const* d_in, const int* in_sizes, int n_in,
                              void* d_out, int out_size, void* d_ws, size_t ws_size,
                              hipStream_t stream) {
    const float* x    = (const float*)d_in[0];
    const float* W    = (const float*)d_in[1];
    const float* C    = (const float*)d_in[2];
    const float* bias = (const float*)d_in[3];
    float* out = (float*)d_out;

    char* ws = (char*)d_ws;
    char*  Arow     = ws;                               // 8192*7168 = 58,720,256
    char*  Brow     = ws + 58720256;                    // 1024*7168 =  7,340,032
    float* bias_aug = (float*)(ws + 66060288);          // 4 KB
    float* scaleC   = (float*)(ws + 66064384);          // 4 KB

    hipLaunchKernelGGL(act_kernel, dim3(TOKENS * IN_F / 8 / 256), dim3(256), 0, stream,
                       x, Arow);
    hipLaunchKernelGGL(wt_kernel, dim3(OUT_F), dim3(256), 0, stream,
                       W, C, bias, Brow, scaleC, bias_aug);
    hipLaunchKernelGGL(gemm_kernel, dim3(512), dim3(256), 0, stream,
                       Arow, Brow, scaleC, bias_aug, out);
}